// Round 15
// baseline (719.984 us; speedup 1.0000x reference)
//
#include <hip/hip_runtime.h>
#include <hip/hip_bf16.h>

// Graph net: 4x (agg = A@h + h; h = tanh((agg@W + b)/deg1)); concat -> graph sum-pool -> relu(linear)
// N=100000, E=3200000, G=64, feats 32, latent [32,32,32,1], out 128.
//
// R15 == R14 resubmit (R14 hit an infra failure, never measured).
// R14: bf16 shadow gather. R13 evidence: layer_fused 85us, FETCH 189MB vs 410MB
// logical gather (54% L2 hit; 12.8MB h vs 4MB/XCD L2) -> L2-fill bound.
// (1) bf16 copy of h for neighbor gathers only (row = 64B = 1 line; halves both
//     request bytes and L2 footprint); fp32 h kept for self/MLP/pooling, so the
//     bf16 error enters only agg (then x W~0.1, /deg~33 -> ~1e-4 per layer).
// (2) CSR pairs packed to one int (src | (dst&511)<<17) -> halves part/csr traffic.

#define NFEAT 32
#define TOTLAT 97
#define NGRAPH 64
#define OUTDIM 128
#define BSHIFT 9            // 512 nodes per bucket
#define NPB 512
#define MAXBUCK 256
#define CH 8192

__device__ __forceinline__ float ftanh(float x) {
    x = fminf(fmaxf(x, -15.0f), 15.0f);
    float t = __expf(2.0f * x);
    return (t - 1.0f) / (t + 1.0f);
}
__device__ __forceinline__ unsigned short f2b(float f) {   // RNE to bf16
    unsigned int x = __float_as_uint(f);
    return (unsigned short)((x + 0x7FFFu + ((x >> 16) & 1u)) >> 16);
}
__device__ __forceinline__ float b2f(unsigned short u) {
    return __uint_as_float(((unsigned int)u) << 16);
}

// ---------------- node_feat -> bf16 copy ----------------
__global__ __launch_bounds__(256) void conv_kernel(const float* __restrict__ in,
                                                   unsigned short* __restrict__ outb, int total4) {
    int i = blockIdx.x * blockDim.x + threadIdx.x;
    if (i >= total4) return;
    float4 v = ((const float4*)in)[i];
    ushort4 o;
    o.x = f2b(v.x); o.y = f2b(v.y); o.z = f2b(v.z); o.w = f2b(v.w);
    ((ushort4*)outb)[i] = o;
}

// ---------------- CSR build ----------------
__global__ __launch_bounds__(256) void hist_kernel(const int* __restrict__ dst,
                                                   int* __restrict__ bucket_cnt,
                                                   int E, int nbuck) {
    __shared__ int h[MAXBUCK];
    for (int i = threadIdx.x; i < nbuck; i += blockDim.x) h[i] = 0;
    __syncthreads();
    int e0 = blockIdx.x * CH, e1 = min(e0 + CH, E);
    const int4* d4 = (const int4*)dst;
    int k0 = e0 >> 2, nk = (e1 - e0) >> 2;
    for (int k = k0 + threadIdx.x; k < k0 + nk; k += blockDim.x) {
        int4 v = d4[k];
        atomicAdd(&h[v.x >> BSHIFT], 1);
        atomicAdd(&h[v.y >> BSHIFT], 1);
        atomicAdd(&h[v.z >> BSHIFT], 1);
        atomicAdd(&h[v.w >> BSHIFT], 1);
    }
    for (int e = e0 + (nk << 2) + threadIdx.x; e < e1; e += blockDim.x)
        atomicAdd(&h[dst[e] >> BSHIFT], 1);
    __syncthreads();
    for (int i = threadIdx.x; i < nbuck; i += blockDim.x)
        if (h[i]) atomicAdd(&bucket_cnt[i], h[i]);
}

__global__ void bucket_scan_kernel(const int* __restrict__ bucket_cnt,
                                   int* __restrict__ bucket_start,
                                   int* __restrict__ bucket_cursor,
                                   int* __restrict__ row_ptr,
                                   int N, int E, int nbuck) {
    __shared__ int s[MAXBUCK];
    int i = threadIdx.x;
    int v = (i < nbuck) ? bucket_cnt[i] : 0;
    s[i] = v;
    __syncthreads();
    for (int d = 1; d < MAXBUCK; d <<= 1) {
        int t = (i >= d) ? s[i - d] : 0;
        __syncthreads();
        if (i >= d) s[i] += t;
        __syncthreads();
    }
    if (i < nbuck) {
        int excl = s[i] - v;
        bucket_start[i] = excl;
        bucket_cursor[i] = excl;
    }
    if (i == 0) { bucket_start[nbuck] = E; row_ptr[N] = E; }
}

// pack: src (17 bits) | local dst (9 bits) << 17
__global__ __launch_bounds__(256) void part_kernel(const int* __restrict__ src,
                                                   const int* __restrict__ dst,
                                                   int* __restrict__ bucket_cursor,
                                                   int* __restrict__ pairs,
                                                   int E, int nbuck) {
    __shared__ int h[MAXBUCK];
    __shared__ int gb[MAXBUCK];
    for (int i = threadIdx.x; i < nbuck; i += blockDim.x) h[i] = 0;
    __syncthreads();
    int e0 = blockIdx.x * CH, e1 = min(e0 + CH, E);
    const int4* d4 = (const int4*)dst;
    const int4* s4 = (const int4*)src;
    int k0 = e0 >> 2, nk = (e1 - e0) >> 2;
    for (int k = k0 + threadIdx.x; k < k0 + nk; k += blockDim.x) {
        int4 v = d4[k];
        atomicAdd(&h[v.x >> BSHIFT], 1);
        atomicAdd(&h[v.y >> BSHIFT], 1);
        atomicAdd(&h[v.z >> BSHIFT], 1);
        atomicAdd(&h[v.w >> BSHIFT], 1);
    }
    for (int e = e0 + (nk << 2) + threadIdx.x; e < e1; e += blockDim.x)
        atomicAdd(&h[dst[e] >> BSHIFT], 1);
    __syncthreads();
    for (int i = threadIdx.x; i < nbuck; i += blockDim.x) {
        int c = h[i];
        gb[i] = c ? atomicAdd(&bucket_cursor[i], c) : 0;
        h[i] = 0;
    }
    __syncthreads();
    for (int k = k0 + threadIdx.x; k < k0 + nk; k += blockDim.x) {
        int4 d = d4[k];
        int4 s = s4[k];
        int b, r;
        b = d.x >> BSHIFT; r = atomicAdd(&h[b], 1); pairs[gb[b] + r] = s.x | ((d.x & 511) << 17);
        b = d.y >> BSHIFT; r = atomicAdd(&h[b], 1); pairs[gb[b] + r] = s.y | ((d.y & 511) << 17);
        b = d.z >> BSHIFT; r = atomicAdd(&h[b], 1); pairs[gb[b] + r] = s.z | ((d.z & 511) << 17);
        b = d.w >> BSHIFT; r = atomicAdd(&h[b], 1); pairs[gb[b] + r] = s.w | ((d.w & 511) << 17);
    }
    for (int e = e0 + (nk << 2) + threadIdx.x; e < e1; e += blockDim.x) {
        int dv = dst[e];
        int b = dv >> BSHIFT;
        int r = atomicAdd(&h[b], 1);
        pairs[gb[b] + r] = src[e] | ((dv & 511) << 17);
    }
}

__global__ __launch_bounds__(NPB) void csr_kernel(const int* __restrict__ pairs,
                                                  const int* __restrict__ bucket_start,
                                                  int* __restrict__ row_ptr,
                                                  int* __restrict__ col_idx,
                                                  float* __restrict__ inv_deg, int N) {
    __shared__ int deg[NPB];
    __shared__ int scn[NPB];
    int b = blockIdx.x;
    int tid = threadIdx.x;
    deg[tid] = 0;
    __syncthreads();
    int e0 = bucket_start[b], e1 = bucket_start[b + 1];
    for (int e = e0 + tid; e < e1; e += NPB) {
        int p = pairs[e];
        atomicAdd(&deg[((unsigned)p) >> 17], 1);
    }
    __syncthreads();
    int v = deg[tid];
    scn[tid] = v;
    __syncthreads();
    for (int d = 1; d < NPB; d <<= 1) {
        int t = (tid >= d) ? scn[tid - d] : 0;
        __syncthreads();
        if (tid >= d) scn[tid] += t;
        __syncthreads();
    }
    int excl = scn[tid] - v;
    int n = (b << BSHIFT) + tid;
    if (n < N) {
        row_ptr[n] = e0 + excl;
        inv_deg[n] = 1.0f / ((float)v + 1.0f);
    }
    deg[tid] = excl;
    __syncthreads();
    for (int e = e0 + tid; e < e1; e += NPB) {
        int p = pairs[e];
        int r = atomicAdd(&deg[((unsigned)p) >> 17], 1);
        col_idx[e0 + r] = p & 0x1FFFF;
    }
}

// ---------------- fused layer: bf16 gather + fp32 MLP (+bf16 out / +y) ----------------
// 8 lanes/node; neighbor rows read as bf16 (64B line), self/MLP in fp32.
template <bool WRITE_B, bool WRITE_Y>
__global__ __launch_bounds__(256, 8) void layer_fused(
    const float* __restrict__ h_in, const unsigned short* __restrict__ hb_in,
    float* __restrict__ h_out, unsigned short* __restrict__ hb_out,
    const float* __restrict__ W, const float* __restrict__ bvec,
    const int* __restrict__ row_ptr, const int* __restrict__ col_idx,
    const float* __restrict__ inv_deg,
    const float* __restrict__ W3, float* __restrict__ y, int N)
{
    __shared__ float accs[32][33];
    const int t = blockIdx.x * blockDim.x + threadIdx.x;
    int n = t >> 3;
    const int l8 = t & 7;
    const bool valid = n < N;
    if (!valid) n = N - 1;

    const float4* __restrict__ h4 = (const float4*)h_in;
    const ushort4* __restrict__ hb4 = (const ushort4*)hb_in;   // 8B = 4 bf16 per lane

    int beg = row_ptr[n];
    int end = row_ptr[n + 1];
    int len = end - beg;
    float4 self = h4[(size_t)n * 8 + l8];
    ushort4 sb = hb4[(size_t)n * 8 + l8];   // bf16(self) for exact pad correction
    float4 acc = self;

    for (int e = beg; e < end; e += 32) {
        int base = e + l8 * 4;
        int my0 = __builtin_nontemporal_load(&col_idx[base + 0]);
        int my1 = __builtin_nontemporal_load(&col_idx[base + 1]);
        int my2 = __builtin_nontemporal_load(&col_idx[base + 2]);
        int my3 = __builtin_nontemporal_load(&col_idx[base + 3]);
        int rem = end - e;
#pragma unroll
        for (int sl = 0; sl < 8; ++sl) {
            int i0 = __shfl(my0, sl, 8);
            int i1 = __shfl(my1, sl, 8);
            int i2 = __shfl(my2, sl, 8);
            int i3 = __shfl(my3, sl, 8);
            int j = sl * 4;
            i0 = (j + 0 < rem) ? i0 : n;
            i1 = (j + 1 < rem) ? i1 : n;
            i2 = (j + 2 < rem) ? i2 : n;
            i3 = (j + 3 < rem) ? i3 : n;
            ushort4 v0 = hb4[(size_t)i0 * 8 + l8];
            ushort4 v1 = hb4[(size_t)i1 * 8 + l8];
            ushort4 v2 = hb4[(size_t)i2 * 8 + l8];
            ushort4 v3 = hb4[(size_t)i3 * 8 + l8];
            acc.x += b2f(v0.x) + b2f(v1.x) + b2f(v2.x) + b2f(v3.x);
            acc.y += b2f(v0.y) + b2f(v1.y) + b2f(v2.y) + b2f(v3.y);
            acc.z += b2f(v0.z) + b2f(v1.z) + b2f(v2.z) + b2f(v3.z);
            acc.w += b2f(v0.w) + b2f(v1.w) + b2f(v2.w) + b2f(v3.w);
        }
    }
    // remove the k padded bf16(self) contributions (exact)
    float fk = (float)(((len + 31) & ~31) - len);
    acc.x -= fk * b2f(sb.x); acc.y -= fk * b2f(sb.y);
    acc.z -= fk * b2f(sb.z); acc.w -= fk * b2f(sb.w);

    // ---- MLP epilogue (same-wave LDS, no barrier) ----
    const int gl = threadIdx.x >> 3;
    const int f0 = l8 * 4;
    accs[gl][f0 + 0] = acc.x;
    accs[gl][f0 + 1] = acc.y;
    accs[gl][f0 + 2] = acc.z;
    accs[gl][f0 + 3] = acc.w;

    float4 o = *(const float4*)&bvec[f0];
#pragma unroll 8
    for (int k = 0; k < NFEAT; ++k) {
        float a = accs[gl][k];
        float4 w = *(const float4*)&W[k * NFEAT + f0];
        o.x += a * w.x; o.y += a * w.y; o.z += a * w.z; o.w += a * w.w;
    }
    float ideg = inv_deg[n];
    float4 v;
    v.x = ftanh(o.x * ideg);
    v.y = ftanh(o.y * ideg);
    v.z = ftanh(o.z * ideg);
    v.w = ftanh(o.w * ideg);

    if (valid) {
        *(float4*)&h_out[(size_t)n * NFEAT + f0] = v;
        if (WRITE_B) {
            ushort4 ob;
            ob.x = f2b(v.x); ob.y = f2b(v.y); ob.z = f2b(v.z); ob.w = f2b(v.w);
            ((ushort4*)hb_out)[(size_t)n * 8 + l8] = ob;
        }
        if (WRITE_Y) {
            float4 wv = *(const float4*)&W3[f0];
            float p = v.x * wv.x + v.y * wv.y + v.z * wv.z + v.w * wv.w;
            p += __shfl_xor(p, 1);
            p += __shfl_xor(p, 2);
            p += __shfl_xor(p, 4);
            if (l8 == 0) y[n] = p;
        }
    }
}

// ---------------- layer 3: scalar gather over y -> z ----------------
__global__ __launch_bounds__(256) void agg3_kernel(
    const float* __restrict__ y, const float* __restrict__ b3,
    const int* __restrict__ row_ptr, const int* __restrict__ col_idx,
    const float* __restrict__ inv_deg, float* __restrict__ z, int N)
{
    int n = blockIdx.x * blockDim.x + threadIdx.x;
    if (n >= N) return;

    int beg = row_ptr[n];
    int end = row_ptr[n + 1];
    float s = y[n];
    int e = beg;
    for (; e + 8 <= end; e += 8) {
        float a0 = y[col_idx[e + 0]];
        float a1 = y[col_idx[e + 1]];
        float a2 = y[col_idx[e + 2]];
        float a3 = y[col_idx[e + 3]];
        float a4 = y[col_idx[e + 4]];
        float a5 = y[col_idx[e + 5]];
        float a6 = y[col_idx[e + 6]];
        float a7 = y[col_idx[e + 7]];
        s += ((a0 + a1) + (a2 + a3)) + ((a4 + a5) + (a6 + a7));
    }
    for (; e < end; ++e)
        s += y[col_idx[e]];

    z[n] = ftanh((s + b3[0]) * inv_deg[n]);
}

// ---------------- pooling: 64 graphs x 4 quarters ----------------
__global__ __launch_bounds__(128) void pool_kernel(
    const float* __restrict__ h0, const float* __restrict__ h1,
    const float* __restrict__ h2, const float* __restrict__ z,
    const int* __restrict__ graph_ids, float* __restrict__ pooled, int N)
{
    __shared__ int sb[2];
    int g = blockIdx.x >> 2, q = blockIdx.x & 3;
    if (threadIdx.x == 0) {
        int lo = 0, hi = N;
        while (lo < hi) { int m = (lo + hi) >> 1; if (graph_ids[m] < g) lo = m + 1; else hi = m; }
        sb[0] = lo;
        lo = 0; hi = N;
        while (lo < hi) { int m = (lo + hi) >> 1; if (graph_ids[m] < g + 1) lo = m + 1; else hi = m; }
        sb[1] = lo;
    }
    __syncthreads();
    int s = sb[0], e = sb[1];
    int per = (e - s + 3) >> 2;
    int ns = s + q * per;
    int ne = min(ns + per, e);
    int c = threadIdx.x;
    if (c >= TOTLAT || ns >= ne) return;

    float sum = 0.0f;
    if (c < 32) {
        const float* p = h0 + c;
#pragma unroll 4
        for (int n = ns; n < ne; ++n) sum += p[(size_t)n * NFEAT];
    } else if (c < 64) {
        const float* p = h1 + (c - 32);
#pragma unroll 4
        for (int n = ns; n < ne; ++n) sum += p[(size_t)n * NFEAT];
    } else if (c < 96) {
        const float* p = h2 + (c - 64);
#pragma unroll 4
        for (int n = ns; n < ne; ++n) sum += p[(size_t)n * NFEAT];
    } else {
#pragma unroll 4
        for (int n = ns; n < ne; ++n) sum += z[n];
    }
    atomicAdd(&pooled[g * TOTLAT + c], sum);
}

__global__ void final_kernel(const float* __restrict__ pooled, const float* __restrict__ Wout,
                             const float* __restrict__ bout, float* __restrict__ out) {
    int g = blockIdx.x;
    int o = threadIdx.x;
    float s = bout[o];
#pragma unroll 4
    for (int k = 0; k < TOTLAT; ++k)
        s += pooled[g * TOTLAT + k] * Wout[k * OUTDIM + o];
    out[g * OUTDIM + o] = fmaxf(s, 0.0f);
}

extern "C" void kernel_launch(void* const* d_in, const int* in_sizes, int n_in,
                              void* d_out, int out_size, void* d_ws, size_t ws_size,
                              hipStream_t stream) {
    const float* node_feat = (const float*)d_in[0];
    const int*   src       = (const int*)d_in[1];
    const int*   dst       = (const int*)d_in[2];
    const int*   graph_ids = (const int*)d_in[3];
    const float* W0 = (const float*)d_in[5];
    const float* b0 = (const float*)d_in[6];
    const float* W1 = (const float*)d_in[7];
    const float* b1 = (const float*)d_in[8];
    const float* W2 = (const float*)d_in[9];
    const float* b2 = (const float*)d_in[10];
    const float* W3 = (const float*)d_in[11];
    const float* b3 = (const float*)d_in[12];
    const float* Wout = (const float*)d_in[13];
    const float* bout = (const float*)d_in[14];
    float* out = (float*)d_out;

    const int N = in_sizes[0] / NFEAT;   // 100000
    const int E = in_sizes[1];           // 3200000
    const int nbuck = (N + NPB - 1) >> BSHIFT;   // 196

    char* ws = (char*)d_ws;
    size_t off = 0;
    auto carve = [&](size_t bytes) -> void* {
        void* p = ws + off;
        off = (off + bytes + 255) & ~(size_t)255;
        return p;
    };
    int*            bucket_cnt    = (int*)carve((size_t)MAXBUCK * 4);
    int*            bucket_start  = (int*)carve((size_t)(MAXBUCK + 1) * 4);
    int*            bucket_cursor = (int*)carve((size_t)MAXBUCK * 4);
    int*            row_ptr       = (int*)carve((size_t)(N + 1) * 4);
    int*            col_idx       = (int*)carve((size_t)(E + 32) * 4);
    float*          inv_deg       = (float*)carve((size_t)N * 4);
    float*          hA            = (float*)carve((size_t)N * NFEAT * 4);
    float*          hB            = (float*)carve((size_t)N * NFEAT * 4);
    float*          hC            = (float*)carve((size_t)N * NFEAT * 4);
    unsigned short* nfb           = (unsigned short*)carve((size_t)N * NFEAT * 2);
    unsigned short* hAb           = (unsigned short*)carve((size_t)N * NFEAT * 2);
    unsigned short* hBb           = (unsigned short*)carve((size_t)N * NFEAT * 2);
    float*          y             = (float*)carve((size_t)N * 4);
    float*          z             = (float*)carve((size_t)N * 4);
    float*          pooled        = (float*)carve((size_t)NGRAPH * TOTLAT * 4);
    // packed pairs (E*4B = 12.8MB) aliases hA (12.8MB; dead before layer 0 writes hA)
    int*            pairs         = (int*)hA;

    hipMemsetAsync(bucket_cnt, 0, (size_t)MAXBUCK * 4, stream);
    hipMemsetAsync(pooled, 0, (size_t)NGRAPH * TOTLAT * 4, stream);

    conv_kernel<<<(N * NFEAT / 4 + 255) / 256, 256, 0, stream>>>(node_feat, nfb, N * NFEAT / 4);

    const int nchunks = (E + CH - 1) / CH;
    hist_kernel<<<nchunks, 256, 0, stream>>>(dst, bucket_cnt, E, nbuck);
    bucket_scan_kernel<<<1, MAXBUCK, 0, stream>>>(bucket_cnt, bucket_start, bucket_cursor,
                                                  row_ptr, N, E, nbuck);
    part_kernel<<<nchunks, 256, 0, stream>>>(src, dst, bucket_cursor, pairs, E, nbuck);
    csr_kernel<<<nbuck, NPB, 0, stream>>>(pairs, bucket_start, row_ptr, col_idx, inv_deg, N);

    const int lblocks = (N * 8 + 255) / 256;
    // L0: self node_feat, gather nfb -> hA + hAb
    layer_fused<true, false><<<lblocks, 256, 0, stream>>>(node_feat, nfb, hA, hAb, W0, b0,
                                                          row_ptr, col_idx, inv_deg,
                                                          nullptr, nullptr, N);
    // L1: self hA, gather hAb -> hB + hBb
    layer_fused<true, false><<<lblocks, 256, 0, stream>>>(hA, hAb, hB, hBb, W1, b1,
                                                          row_ptr, col_idx, inv_deg,
                                                          nullptr, nullptr, N);
    // L2: self hB, gather hBb -> hC + y (no bf16 out)
    layer_fused<false, true><<<lblocks, 256, 0, stream>>>(hB, hBb, hC, nullptr, W2, b2,
                                                          row_ptr, col_idx, inv_deg,
                                                          W3, y, N);
    agg3_kernel<<<(N + 255) / 256, 256, 0, stream>>>(y, b3, row_ptr, col_idx, inv_deg, z, N);

    pool_kernel<<<NGRAPH * 4, 128, 0, stream>>>(hA, hB, hC, z, graph_ids, pooled, N);
    final_kernel<<<NGRAPH, OUTDIM, 0, stream>>>(pooled, Wout, bout, out);
}